// Round 4
// baseline (73.352 us; speedup 1.0000x reference)
//
#include <hip/hip_runtime.h>
#include <hip/hip_bf16.h>

// Problem constants
#define IMGX   144
#define PATCH  4
#define NPS    36      // patches per side
#define NTOKB  1296    // tokens per batch
#define ED     16      // embedding dim
#define BATCH  4
#define NTOK   5184    // total tokens (BATCH * NTOKB)
#define CH     64      // tokens staged per LDS chunk (one per lane)
#define LSTRIDE 20     // LDS dwords per token: 8 lanes * 20 % 32 sweeps all 32 banks -> conflict-free b128
#define PREP_BLOCKS 21 // ceil(5184 / 256)

// Module-scope scratch (load-time allocated; no d_ws, no capture-unsafe memset).
// Cross-kernel visibility via same-stream dispatch ordering.
__device__ float g_partial[PREP_BLOCKS];  // per-block input maxima
__device__ float g_norms[NTOK];           // per-token squared norms (raw x)

// Kernel 1: per-token squared norms + per-block max (no atomics, no init needed).
__global__ __launch_bounds__(256) void prep_kernel(const float* __restrict__ x) {
    __shared__ float wmax[4];
    const int tid = threadIdx.x;
    const int t = blockIdx.x * 256 + tid;
    float m = 0.0f;
    if (t < NTOK) {
        const float4* p = (const float4*)(x + t * ED);  // 16 f32 = 64B, 16B-aligned
        float v[16];
        float4* v4 = (float4*)v;
        v4[0] = p[0];
        v4[1] = p[1];
        v4[2] = p[2];
        v4[3] = p[3];
        float ns = 0.0f;
#pragma unroll
        for (int k = 0; k < 16; k++) {
            ns = fmaf(v[k], v[k], ns);
            m = fmaxf(m, v[k]);  // x >= 0 (uniform[0,1)), so 0-init is safe
        }
        g_norms[t] = ns;
    }
#pragma unroll
    for (int s = 32; s; s >>= 1) m = fmaxf(m, __shfl_xor(m, s));
    if ((tid & 63) == 0) wmax[tid >> 6] = m;
    __syncthreads();
    if (tid == 0) {
        float bm = fmaxf(fmaxf(wmax[0], wmax[1]), fmaxf(wmax[2], wmax[3]));
        g_partial[blockIdx.x] = bm;
    }
}

// Kernel 2: fused attention + merging. One wave per row i; 4 waves (rows) per
// block, all rows of a block in the same batch. Tokens staged per 64-token
// chunk into LDS.
//
// Math: logit[i,j] = -mean_d((xn_i - xn_j)^2), xn = x/xmax
//     = s*(2*x_i.x_j - n_i - n_j),  s = 1/(16*xmax^2),  n_t = ||x_t||^2 (raw x).
// Row-constant -s*n_i drops out of softmax; remaining logit' = s*(2*dot - n_j)
// has analytic row max s*n_i (full logit <= 0 with equality at j=i).
// So p_j = exp(s*(2*dot - n_j) - s*n_i) in (0,1] -- no online softmax, and
// denom >= 1 always (the j=i term is exactly 1).
// Accumulate raw x_j: out*xmax = attn @ x, so xmax never divides anything.
__global__ __launch_bounds__(256) void attn_kernel(const float* __restrict__ x,
                                                   float* __restrict__ out) {
    __shared__ float lds[CH * LSTRIDE];

    const int tid  = threadIdx.x;
    const int lane = tid & 63;
    const int wave = tid >> 6;
    const int blk  = blockIdx.x;              // 0..1295
    const int b    = blk / 324;               // 324 blocks per batch
    const int i    = (blk % 324) * 4 + wave;  // row (query token) in batch

    const float* xb = x + b * (NTOKB * ED);
    const float* norms = g_norms + b * NTOKB;

    // Global max from the 21 prep partials. FULL 64-lane butterfly (s starts
    // at 32): round-3 bug was s=16, which left lanes 32-63 with xmax=0 -> inf
    // -> NaN through the o/denom reduction.
    float pm = (lane < PREP_BLOCKS) ? g_partial[lane] : 0.0f;
#pragma unroll
    for (int sh = 32; sh; sh >>= 1) pm = fmaxf(pm, __shfl_xor(pm, sh));
    const float xmax = pm;
    const float s = 1.0f / (16.0f * xmax * xmax);

    // Query token t_i (16 contiguous floats -- tokens are 1x16 row strips)
    float ti[16];
    {
        const float4* p = (const float4*)(xb + i * ED);
        float4* t4 = (float4*)ti;
        t4[0] = p[0];
        t4[1] = p[1];
        t4[2] = p[2];
        t4[3] = p[3];
    }
    const float m = s * norms[i];  // analytic row max of the reduced logits

    float o[16];
#pragma unroll
    for (int d = 0; d < 16; d++) o[d] = 0.0f;
    float denom = 0.0f;

    const int tok = tid >> 2;  // staging map: thread -> (token, quad)
    const int q   = tid & 3;

    for (int j0 = 0; j0 < NTOKB; j0 += CH) {
        __syncthreads();
        {
            int j = j0 + tok;
            if (j < NTOKB) {
                const float4 v = *((const float4*)(xb + j * ED + q * 4));  // coalesced 16B
                *((float4*)&lds[tok * LSTRIDE + q * 4]) = v;
            }
        }
        __syncthreads();

        const int jj = j0 + lane;
        if (jj < NTOKB) {
            float tj[16];
            float4* tj4 = (float4*)tj;
            const float4* lp = (const float4*)&lds[lane * LSTRIDE];  // 80B stride, 16B aligned
            tj4[0] = lp[0];
            tj4[1] = lp[1];
            tj4[2] = lp[2];
            tj4[3] = lp[3];

            const float nj = norms[jj];
            float dot = 0.0f;
#pragma unroll
            for (int d = 0; d < 16; d++) dot = fmaf(ti[d], tj[d], dot);

            // p = exp(s*(2*dot - nj) - m), guaranteed in (0, 1]
            const float pj = __expf(fmaf(s, fmaf(2.0f, dot, -nj), -m));
            denom += pj;
#pragma unroll
            for (int d = 0; d < 16; d++) o[d] = fmaf(pj, tj[d], o[d]);
        }
    }

    // Butterfly reduction of {denom, o[0..15]} across the 64-lane wave
#pragma unroll
    for (int sh = 32; sh; sh >>= 1) {
        denom += __shfl_xor(denom, sh);
#pragma unroll
        for (int d = 0; d < 16; d++) o[d] += __shfl_xor(o[d], sh);
    }

    const float inv = 1.0f / denom;

    // Merging permutation: row i -> patch (by,bx); element d=(ky,kx) -> pixel
    // (by*4+ky, bx*4+kx). Output already in raw-x units.
    if (lane < 4) {
        const int by = i / NPS;
        const int bx = i % NPS;
        const int ky = lane;
        float4 sv;
        sv.x = o[ky * 4 + 0] * inv;
        sv.y = o[ky * 4 + 1] * inv;
        sv.z = o[ky * 4 + 2] * inv;
        sv.w = o[ky * 4 + 3] * inv;
        float* dst = out + b * (IMGX * IMGX) + (by * PATCH + ky) * IMGX + bx * PATCH;
        *((float4*)dst) = sv;  // 16B aligned: (row*144 + bx*4)*4
    }
}

extern "C" void kernel_launch(void* const* d_in, const int* in_sizes, int n_in,
                              void* d_out, int out_size, void* d_ws, size_t ws_size,
                              hipStream_t stream) {
    const float* x = (const float*)d_in[0];  // f32 input (4,1,144,144)
    float* out = (float*)d_out;              // f32 output (4,1,144,144)
    (void)d_ws; (void)ws_size;               // scratch lives in __device__ globals

    hipLaunchKernelGGL(prep_kernel, dim3(PREP_BLOCKS), dim3(256), 0, stream, x);
    hipLaunchKernelGGL(attn_kernel, dim3(1296), dim3(256), 0, stream, x, out);
}